// Round 7
// baseline (373.317 us; speedup 1.0000x reference)
//
#include <hip/hip_runtime.h>

// LongConvBlock, round 7: single persistent kernel with hand-rolled grid
// barrier (cooperative-launch API was rejected in R6; counter barrier works
// because 512 blocks x 59.9KB LDS = exactly 2 blocks/CU co-resident).
// out[b,l,h] = sum_j x[b,j,h] * k'[h,l-j],  k'[0] += D[h].
//
// Phase 1: x [B,L,H] f32 -> xT [B][H][PADX+L] bf16 (+left pad), 8 tiles/blk.
// Phase 2: per block 2 h: stage x window (b-XOR swizzle) + build reversed
//   soft-thresholded k band (2 parity copies) in LDS from kin; R5 A-shared
//   affine MFMA loop; writeout packed bf16 -> outT[b][h][l].
// Phase 3: outT -> out f32 [B][L][H], 8 tiles/blk.
// Barriers: monotone global counter, agent-scope atomics + __threadfence
// (flushes per-XCD L2 so cross-XCD handoffs of xT/outT are safe; each 64B
// line is written by exactly one block -> no false sharing).

typedef __attribute__((ext_vector_type(8)))  short s16x8;   // 8 bf16
typedef __attribute__((ext_vector_type(16))) float f32x16;  // 32x32 acc
typedef __attribute__((ext_vector_type(4)))  float f32x4;
typedef __attribute__((ext_vector_type(4)))  unsigned int u32x4;

constexpr int B_ = 4, L_ = 4096, H_ = 1024;
constexpr int PADX = 256;
constexpr int LX = L_ + PADX;    // 4352 xT row
constexpr int LK = L_ + 32;      // 4128 k band row
constexpr int ST = 256;          // outputs per (wave, si)

constexpr size_t XT_ELEMS = (size_t)B_ * H_ * LX;
constexpr size_t OT_ELEMS = (size_t)B_ * H_ * L_;
constexpr size_t WS_NEEDED = (XT_ELEMS + OT_ELEMS) * sizeof(unsigned short) + 64;

constexpr int XS_ROW  = 4320;           // x window per b (l in [-224,4095])
constexpr int XS_BLKS = XS_ROW / 8;     // 540
constexpr int XS_US   = B_ * XS_ROW;    // 17280
constexpr int KS_US   = 2 * LK;         // 8256
constexpr int OAREA_DW = 4 * 132;       // 528 dwords per wave
constexpr int SMEM_BYTES = XS_US * 2 + KS_US * 2 + 4 * OAREA_DW * 4;  // 59520

constexpr int nHt = H_ / 64, nLt = L_ / 64;
constexpr int NXB = B_ * nLt * nHt;     // 4096 transpose tiles
constexpr int GRID = 512;               // 2 blocks/CU (LDS-bound) -> co-resident

__device__ __forceinline__ unsigned short f2bf(float f) {
    unsigned int u = __builtin_bit_cast(unsigned int, f);
    u += 0x7fffu + ((u >> 16) & 1u);    // RTNE
    return (unsigned short)(u >> 16);
}
__device__ __forceinline__ float bf2f(unsigned short u) {
    return __builtin_bit_cast(float, (unsigned int)u << 16);
}

__device__ __forceinline__ void grid_barrier(unsigned int* cnt, unsigned int target) {
    __syncthreads();
    if (threadIdx.x == 0) {
        __threadfence();   // agent-scope release: flush dirty L2 before signal
        __hip_atomic_fetch_add(cnt, 1u, __ATOMIC_ACQ_REL, __HIP_MEMORY_SCOPE_AGENT);
        while (__hip_atomic_load(cnt, __ATOMIC_ACQUIRE, __HIP_MEMORY_SCOPE_AGENT) < target) {
            __builtin_amdgcn_s_sleep(8);
        }
        __threadfence();   // acquire side: invalidate stale caches
    }
    __syncthreads();
}

// One 16-chunk body: shared A-frag -> up to 4 MFMAs; all offsets immediate.
#define BODY(DO0, DO1, DO2, DO3)                                            \
  {                                                                         \
    _Pragma("unroll")                                                       \
    for (int i = 0; i < 16; ++i) {                                          \
      u32x4 aw;                                                             \
      aw.x = abase[8*i+0]; aw.y = abase[8*i+1];                             \
      aw.z = abase[8*i+2]; aw.w = abase[8*i+3];                             \
      const s16x8 af = __builtin_bit_cast(s16x8, aw);                       \
      const int io = 32 * (i >> 1);                                         \
      if (DO3) acc3 = __builtin_amdgcn_mfma_f32_32x32x16_bf16(              \
            af, *(const s16x8*)(((i & 1) ? t3b : t3a) + io), acc3, 0,0,0);  \
      if (DO2) acc2 = __builtin_amdgcn_mfma_f32_32x32x16_bf16(              \
            af, *(const s16x8*)(((i & 1) ? t2b : t2a) + io), acc2, 0,0,0);  \
      if (DO1) acc1 = __builtin_amdgcn_mfma_f32_32x32x16_bf16(              \
            af, *(const s16x8*)(((i & 1) ? t1b : t1a) + io), acc1, 0,0,0);  \
      if (DO0) acc0 = __builtin_amdgcn_mfma_f32_32x32x16_bf16(              \
            af, *(const s16x8*)(((i & 1) ? t0b : t0a) + io), acc0, 0,0,0);  \
    }                                                                       \
    abase -= 128;                                                           \
    if (DO3) { t3a -= 256; t3b -= 256; }                                    \
    if (DO2) { t2a -= 256; t2b -= 256; }                                    \
    if (DO1) { t1a -= 256; t1b -= 256; }                                    \
    if (DO0) { t0a -= 256; t0b -= 256; }                                    \
  }

__global__ __launch_bounds__(256, 2)
void longconv_fused(const float* __restrict__ x, const float* __restrict__ kin,
                    const float* __restrict__ Dk,
                    unsigned short* __restrict__ xT,
                    unsigned int* __restrict__ outT,
                    float* __restrict__ out,
                    unsigned int* __restrict__ cnt)
{
    __shared__ __align__(16) unsigned char smem[SMEM_BYTES];
    const int bid = blockIdx.x;
    const int j   = threadIdx.x;

    // ================= phase 1: x [B,L,H] f32 -> xT [B][H][LX] bf16 ========
    {
        float (*tile)[65] = (float (*)[65])smem;
        const int h4 = j & 15, rg = j >> 4, lg = j & 7;
        #pragma unroll
        for (int it = 0; it < NXB / GRID; ++it) {
            const int tI = bid + GRID * it;
            const int b  = tI / (nLt * nHt);
            const int r0 = tI % (nLt * nHt);
            const int l0 = (r0 / nHt) * 64;
            const int h0 = (r0 % nHt) * 64;
            __syncthreads();                      // LDS free from prev iter
            #pragma unroll
            for (int rr = 0; rr < 4; ++rr) {
                const int lr = rg + 16 * rr;
                const f32x4 v = *(const f32x4*)(x + ((size_t)b * L_ + l0 + lr) * H_ + h0 + 4 * h4);
                tile[lr][4 * h4 + 0] = v.x; tile[lr][4 * h4 + 1] = v.y;
                tile[lr][4 * h4 + 2] = v.z; tile[lr][4 * h4 + 3] = v.w;
            }
            __syncthreads();
            #pragma unroll
            for (int pp = 0; pp < 2; ++pp) {
                const int hh = (j >> 3) + 32 * pp;
                unsigned int w0 = (unsigned int)f2bf(tile[8*lg+0][hh]) | ((unsigned int)f2bf(tile[8*lg+1][hh]) << 16);
                unsigned int w1 = (unsigned int)f2bf(tile[8*lg+2][hh]) | ((unsigned int)f2bf(tile[8*lg+3][hh]) << 16);
                unsigned int w2 = (unsigned int)f2bf(tile[8*lg+4][hh]) | ((unsigned int)f2bf(tile[8*lg+5][hh]) << 16);
                unsigned int w3 = (unsigned int)f2bf(tile[8*lg+6][hh]) | ((unsigned int)f2bf(tile[8*lg+7][hh]) << 16);
                const u32x4 v = {w0, w1, w2, w3};
                *(u32x4*)(xT + ((size_t)b * H_ + h0 + hh) * LX + PADX + l0 + 8 * lg) = v;
            }
            if (l0 == 0) {                        // left pad zeros
                #pragma unroll
                for (int z = 0; z < 8; ++z) {
                    const int idx = j + 256 * z;  // 2048 vec-blocks
                    const int row = idx >> 5, off = idx & 31;
                    const u32x4 zz = {};
                    *(u32x4*)(xT + ((size_t)b * H_ + h0 + row) * LX + off * 8) = zz;
                }
            }
        }
    }
    grid_barrier(cnt, GRID);

    // ================= phase 2: MFMA main, 2 h per block ====================
    {
        unsigned short* xs = (unsigned short*)smem;
        unsigned short* ks = (unsigned short*)(smem + (size_t)XS_US * 2);
        float* oarea = (float*)(smem + (size_t)XS_US * 2 + (size_t)KS_US * 2);

        const int w  = j >> 6, ln = j & 63;
        const int m  = ln & 31,  q  = ln >> 5;
        const int t  = m >> 2,   b  = m & 3;
        const int si0 = w, si1 = 7 - w, si2 = 8 + w, si3 = 15 - w;
        const int nb = 4 * t + q;

        for (int hi = 0; hi < 2; ++hi) {
            const int h = bid + GRID * hi;
            __syncthreads();                      // xs/ks free from prev h
            // stage x window (b-XOR swizzled 16B blocks)
            constexpr int NXU = XS_BLKS * 4;      // 2160
            for (int u = j; u < NXU; u += 256) {
                const int bb = u / XS_BLKS, n = u - bb * XS_BLKS;
                const u32x4 v = *(const u32x4*)(xT + ((size_t)bb * H_ + h) * LX + 32 + n * 8);
                *(u32x4*)(xs + (size_t)bb * XS_ROW + (size_t)(n ^ bb) * 8) = v;
            }
            // build reversed soft-thresholded k band in LDS (2 parity copies)
            {
                const float Dv = Dk[h];
                #pragma unroll
                for (int it = 0; it < L_ / 256; ++it) {
                    const int l = j + 256 * it;
                    const float a = kin[(size_t)h * L_ + l];
                    float v = copysignf(fmaxf(fabsf(a) - 0.1f, 0.0f), a);
                    if (l == 0) v += Dv;
                    const unsigned short bv = f2bf(v);
                    ks[L_ - 1 - l] = bv;                          // parity 0
                    if (l <= L_ - 2) ks[LK + (L_ - 2 - l)] = bv;  // parity 1
                }
                if (j < 32) ks[L_ + j] = 0;
                if (j < 33) ks[LK + (L_ - 1) + j] = 0;
            }
            __syncthreads();

            // A: frag(r)[j] = ks[p][(base-p) + r + j]
            const int base = 3871 - m + 8 * q;
            const int p    = base & 1;
            const unsigned int* abase = (const unsigned int*)(ks + p * LK + (base - p));
            const unsigned short* xrow = xs + (size_t)b * XS_ROW;
            auto mk = [&](int si, int par) -> const unsigned short* {
                const int n = 32 * si + nb + 2 * par;
                return xrow + (size_t)((n ^ b) * 8);
            };
            const unsigned short *t0a = mk(si0, 0), *t0b = mk(si0, 1);
            const unsigned short *t1a = mk(si1, 0), *t1b = mk(si1, 1);
            const unsigned short *t2a = mk(si2, 0), *t2b = mk(si2, 1);
            const unsigned short *t3a = mk(si3, 0), *t3b = mk(si3, 1);

            f32x16 acc0 = {}, acc1 = {}, acc2 = {}, acc3 = {};
            int beta = 0;
            for (; beta <= si0; ++beta) BODY(1, 1, 1, 1);
            for (; beta <= si1; ++beta) BODY(0, 1, 1, 1);
            for (; beta <= si2; ++beta) BODY(0, 0, 1, 1);
            for (; beta <= si3; ++beta) BODY(0, 0, 0, 1);

            // writeout via per-wave LDS area (t-rotation vs bank conflicts)
            float* ar = oarea + w * OAREA_DW;
            auto writeout = [&](const f32x16& acc, int si) {
                const int Ls = si * ST;
                #pragma unroll
                for (int rh = 0; rh < 2; ++rh) {
                    #pragma unroll
                    for (int rr2 = 0; rr2 < 2; ++rr2) {
                        const int base4 = (8 * rr2 + 4 * q + 4 * t) & 15;
                        f32x4 qd;
                        qd.x = acc[4 * (2 * rh + rr2) + 0];
                        qd.y = acc[4 * (2 * rh + rr2) + 1];
                        qd.z = acc[4 * (2 * rh + rr2) + 2];
                        qd.w = acc[4 * (2 * rh + rr2) + 3];
                        *(f32x4*)(ar + b * 132 + 16 * t + base4) = qd;
                    }
                    __asm__ volatile("s_waitcnt lgkmcnt(0)" ::: "memory");
                    #pragma unroll
                    for (int bb = 0; bb < 4; ++bb) {
                        const int g  = ln >> 3;
                        const int uu = (2 * ln) & 15;
                        const int s  = (uu + 4 * g) & 15;
                        const float v0 = ar[bb * 132 + 16 * g + s];
                        const float v1 = ar[bb * 132 + 16 * g + s + 1];
                        const int l = 32 * g + 16 * rh + uu;
                        const unsigned int pk =
                            (unsigned int)f2bf(v0) | ((unsigned int)f2bf(v1) << 16);
                        outT[(((size_t)bb * H_ + h) * L_ + Ls + l) >> 1] = pk;
                    }
                    __asm__ volatile("s_waitcnt lgkmcnt(0)" ::: "memory");
                }
            };
            writeout(acc0, si0);
            writeout(acc1, si1);
            writeout(acc2, si2);
            writeout(acc3, si3);
        }
    }
    grid_barrier(cnt, 2 * GRID);

    // ================= phase 3: outT bf16 [B][H][L] -> out f32 [B][L][H] ====
    {
        float (*tile)[65] = (float (*)[65])smem;
        const unsigned short* oT = (const unsigned short*)outT;
        const int lg = j & 7, hg = j & 15;
        #pragma unroll
        for (int it = 0; it < NXB / GRID; ++it) {
            const int tI = bid + GRID * it;
            const int b  = tI / (nLt * nHt);
            const int r0 = tI % (nLt * nHt);
            const int l0 = (r0 / nHt) * 64;
            const int h0 = (r0 % nHt) * 64;
            __syncthreads();
            #pragma unroll
            for (int pp = 0; pp < 2; ++pp) {
                const int hh = (j >> 3) + 32 * pp;
                const u32x4 v = *(const u32x4*)(oT + ((size_t)b * H_ + h0 + hh) * L_ + l0 + 8 * lg);
                const unsigned short* pu = (const unsigned short*)&v;
                #pragma unroll
                for (int i = 0; i < 8; ++i) tile[8 * lg + i][hh] = bf2f(pu[i]);
            }
            __syncthreads();
            #pragma unroll
            for (int pp = 0; pp < 4; ++pp) {
                const int ll = (j >> 4) + 16 * pp;
                f32x4 v;
                v.x = tile[ll][4 * hg + 0];
                v.y = tile[ll][4 * hg + 1];
                v.z = tile[ll][4 * hg + 2];
                v.w = tile[ll][4 * hg + 3];
                *(f32x4*)(out + ((size_t)b * L_ + l0 + ll) * H_ + h0 + 4 * hg) = v;
            }
        }
    }
}

// ---- fallback: fp32 direct conv (only if ws too small) ----
constexpr int TLf = 32, Uf = 8, Wf = TLf + Uf - 1, HTf = 256;

__global__ __launch_bounds__(HTf)
void longconv_fp32(const float* __restrict__ x, const float* __restrict__ k,
                   const float* __restrict__ Dskip, float* __restrict__ out)
{
    const int h  = blockIdx.y * HTf + threadIdx.x;
    const int b  = blockIdx.z;
    const int lt = (int)gridDim.x - 1 - (int)blockIdx.x;
    const int L0 = lt * TLf;
    const float* __restrict__ xb = x + ((size_t)b * L_) * H_ + h;
    const float* __restrict__ kh = k + (size_t)h * L_;
    float acc[TLf]; float win[Wf];
    #pragma unroll
    for (int i = 0; i < Wf; ++i) {
        const int idx = L0 - (Uf - 1) + i;
        win[i] = (idx >= 0) ? xb[(size_t)idx * H_] : 0.0f;
    }
    const float Dv = Dskip[h];
    #pragma unroll
    for (int jj = 0; jj < TLf; ++jj) acc[jj] = win[jj + Uf - 1] * Dv;
    const int cmax = L0 / Uf + (TLf / Uf) - 1;
    for (int c = 0; c <= cmax; ++c) {
        float kr[Uf];
        #pragma unroll
        for (int u = 0; u < Uf; ++u) {
            const float a = kh[c * Uf + u];
            kr[u] = copysignf(fmaxf(fabsf(a) - 0.1f, 0.0f), a);
        }
        #pragma unroll
        for (int u = 0; u < Uf; ++u)
            #pragma unroll
            for (int jj = 0; jj < TLf; ++jj)
                acc[jj] = fmaf(kr[u], win[jj + (Uf - 1) - u], acc[jj]);
        if (c < cmax) {
            #pragma unroll
            for (int i = Wf - 1; i >= Uf; --i) win[i] = win[i - Uf];
            #pragma unroll
            for (int i = 0; i < Uf; ++i) {
                const int idx = L0 - (c + 1) * Uf - (Uf - 1) + i;
                win[i] = (idx >= 0) ? xb[(size_t)idx * H_] : 0.0f;
            }
        }
    }
    float* __restrict__ ob = out + ((size_t)b * L_ + L0) * H_ + h;
    #pragma unroll
    for (int jj = 0; jj < TLf; ++jj) ob[(size_t)jj * H_] = acc[jj];
}

extern "C" void kernel_launch(void* const* d_in, const int* in_sizes, int n_in,
                              void* d_out, int out_size, void* d_ws, size_t ws_size,
                              hipStream_t stream)
{
    const float* x   = (const float*)d_in[0];  // [B, L, H]
    const float* kfp = (const float*)d_in[1];  // [1, H, L]
    const float* Dk  = (const float*)d_in[2];  // [1, H]
    float* out = (float*)d_out;                // [B, L, H]

    if (ws_size >= WS_NEEDED) {
        unsigned short* xT  = (unsigned short*)d_ws;
        unsigned int*   oT  = (unsigned int*)(xT + XT_ELEMS);
        unsigned int*   cnt = (unsigned int*)(xT + XT_ELEMS + OT_ELEMS);
        hipMemsetAsync((void*)cnt, 0, 64, stream);   // zero barrier counter
        longconv_fused<<<dim3(GRID), dim3(256), 0, stream>>>(
            x, kfp, Dk, xT, oT, out, cnt);
    } else {
        dim3 grid(L_ / TLf, H_ / HTf, B_);
        longconv_fp32<<<grid, dim3(HTf), 0, stream>>>(x, kfp, Dk, out);
    }
}